// Round 3
// baseline (1363.720 us; speedup 1.0000x reference)
//
#include <hip/hip_runtime.h>
#include <stdint.h>

// ---------------- types ----------------
typedef unsigned short u16;
typedef unsigned long long u64;
typedef __attribute__((ext_vector_type(8))) short  bf16x8;   // 8 bf16 (MFMA A/B frag)
typedef __attribute__((ext_vector_type(8))) u16    u16x8;
typedef __attribute__((ext_vector_type(4))) float  f32x4;

#define MFMA_BF16(a,b,c) __builtin_amdgcn_mfma_f32_16x16x32_bf16((a),(b),(c),0,0,0)

// ---------------- problem constants ----------------
#define BATCH   2048
#define HID     256
#define INP     512
#define FSTEPS  32
#define RSTEPS  3
#define NVF     35            // 32 fwd virtual frames + 3 rev (63,62,61)

// h global buffers: [parity][2048 rows][128 u32]  (256 bf16 cols packed in pairs)
static constexpr size_t HROW32 = 128;                     // u32 per row
static constexpr size_t HPAR32 = (size_t)BATCH * HROW32;  // u32 per parity

// ---------------- ws layout (bytes) ----------------
static constexpr size_t OFF_CTL  = 0;                                  // 4 KB barrier ctl
static constexpr size_t OFF_H0G  = 4096;                               // 2 MiB (2 parities)
static constexpr size_t OFF_H1G  = OFF_H0G + HPAR32 * 2 * 4;
static constexpr size_t OFF_LAT  = OFF_H1G + HPAR32 * 2 * 4;           // latent fp32 (2048x512)
static constexpr size_t OFF_XP   = OFF_LAT + (size_t)BATCH * 512 * 4;  // xproj fp16 [35][2048][1024]
static constexpr size_t XP_BYTES = (size_t)NVF * BATCH * 1024 * 2;
static constexpr size_t OFF_W0XF = OFF_XP + XP_BYTES;                  // Wih0 row-major bf16 [1024][512]
static constexpr size_t OFF_W0XR = OFF_W0XF + (size_t)1024 * 512 * 2;
static constexpr size_t OFF_P0F  = OFF_W0XR + (size_t)1024 * 512 * 2;  // Whh0 frag-packed: 32768 x 16B
static constexpr size_t OFF_P0R  = OFF_P0F + (size_t)32768 * 16;
static constexpr size_t OFF_P1F  = OFF_P0R + (size_t)32768 * 16;       // W1 frag-packed: 65536 x 16B
static constexpr size_t OFF_P1R  = OFF_P1F + (size_t)65536 * 16;
static constexpr size_t OFF_BS0F = OFF_P1R + (size_t)65536 * 16;       // bias sums fp32 [1024]
static constexpr size_t OFF_BS0R = OFF_BS0F + 4096;
static constexpr size_t OFF_BS1F = OFF_BS0R + 4096;
static constexpr size_t OFF_BS1R = OFF_BS1F + 4096;
static constexpr size_t WS_NEED  = OFF_BS1R + 4096;      // ~153 MiB

// ---------------- small helpers ----------------
__device__ __forceinline__ u16 f2bf(float f) {           // RNE f32 -> bf16 bits
    unsigned u = __float_as_uint(f);
    unsigned r = (u + 0x7fffu + ((u >> 16) & 1u)) >> 16;
    return (u16)r;
}
__device__ __forceinline__ float sigm(float x) { return 1.0f / (1.0f + __expf(-x)); }
__device__ __forceinline__ float tanh_fast(float x) {
    float a = fabsf(x);
    float e = __expf(-2.0f * a);
    float t = (1.0f - e) / (1.0f + e);
    return x < 0.0f ? -t : t;
}

// 16-WG group barrier, NO fences. Each wave drains its sc1 stores (vmcnt) before
// arrival; flag ops are relaxed AGENT-scope (coherence-point); poll via loads.
__device__ __forceinline__ void gbar16(unsigned* c) {
    asm volatile("s_waitcnt vmcnt(0)" ::: "memory");   // per-wave: h stores reached coherence point
    __syncthreads();
    if (threadIdx.x == 0) {
        unsigned g = __hip_atomic_load(c + 1, __ATOMIC_RELAXED, __HIP_MEMORY_SCOPE_AGENT);
        unsigned a = __hip_atomic_fetch_add(c, 1u, __ATOMIC_RELAXED, __HIP_MEMORY_SCOPE_AGENT);
        if (a == 15u) {
            __hip_atomic_store(c, 0u, __ATOMIC_RELAXED, __HIP_MEMORY_SCOPE_AGENT);
            __hip_atomic_store(c + 1, g + 1u, __ATOMIC_RELAXED, __HIP_MEMORY_SCOPE_AGENT);
        } else {
            while (__hip_atomic_load(c + 1, __ATOMIC_RELAXED, __HIP_MEMORY_SCOPE_AGENT) == g)
                __builtin_amdgcn_s_sleep(1);
        }
    }
    __syncthreads();
}

// LDS h tile: [128 rows][256 bf16], row stride 512B, XOR swizzle on bits 4-6
__device__ __forceinline__ bf16x8 ldsA(const char* H, int row, int k) {
    int byte = (row << 9) + (k << 1);
    byte ^= (row & 7) << 4;
    return *(const bf16x8*)(H + byte);
}

// reload full 128x256 h tile from global parity buffer (sc1 u64 loads) into LDS
__device__ __forceinline__ void reload_h(char* Hs, const u64* src, int M0, int tid) {
    u64 v[32];
#pragma unroll
    for (int i = 0; i < 32; ++i) {
        int idx = tid + (i << 8);                 // 0..8191
        v[i] = __hip_atomic_load(src + (size_t)(M0 + (idx >> 6)) * 64 + (idx & 63),
                                 __ATOMIC_RELAXED, __HIP_MEMORY_SCOPE_AGENT);
    }
#pragma unroll
    for (int i = 0; i < 32; ++i) {
        int idx = tid + (i << 8);
        int row = idx >> 6, cu = idx & 63;
        int byte = (row << 9) + (cu << 3);
        byte ^= (row & 7) << 4;
        *(u64*)(Hs + byte) = v[i];
    }
}

// store 8 h values (cols = HC0+lane&15, rows per m,r) as packed u32 pairs, sc1
__device__ __forceinline__ void store_h_packed(unsigned* dst32, const float hn[2][4],
                                               int M0, int wv, int lane, int HC0) {
    const int q = (lane >> 4) << 2;
    const int cp = (HC0 >> 1) + ((lane & 15) >> 1);
#pragma unroll
    for (int m = 0; m < 2; ++m)
#pragma unroll
        for (int r = 0; r < 4; ++r) {
            float partner = __shfl_xor(hn[m][r], 1);
            if ((lane & 1) == m) {
                unsigned own = f2bf(hn[m][r]), pb = f2bf(partner);
                unsigned w = (lane & 1) ? ((own << 16) | pb) : (own | (pb << 16));
                int row = M0 + wv * 32 + m * 16 + q + r;
                __hip_atomic_store(dst32 + (size_t)row * HROW32 + cp, w,
                                   __ATOMIC_RELAXED, __HIP_MEMORY_SCOPE_AGENT);
            }
        }
}

// ---------------- persistent sequential kernel ----------------
// 256 WGs x 256 thr, 1/CU. 16 groups of 16 WGs; group = 128 batch rows, member = 16 h-cols.
// Weights: frag-packed in global, consumed from L2 (never invalidated - no fences anywhere).
// LDS: H0s 64KB + H1s 64KB (full group h tiles).
__global__ void __launch_bounds__(256, 1)
lstm_seq(const _Float16* __restrict__ xp,
         const u16* __restrict__ P0f_, const u16* __restrict__ P0r_,
         const u16* __restrict__ P1f_, const u16* __restrict__ P1r_,
         const float* __restrict__ bs1f, const float* __restrict__ bs1r,
         unsigned* __restrict__ h0g, unsigned* __restrict__ h1g,
         float* __restrict__ latent, unsigned* __restrict__ ctl)
{
    extern __shared__ char lds[];
    char* H0s = lds;            // 65536
    char* H1s = lds + 65536;    // 65536

    const int tid = threadIdx.x, wv = tid >> 6, lane = tid & 63;
    const int bid = blockIdx.x;
    const int grp = (bid & 7) * 2 + ((bid >> 3) >> 4);   // 0..15 (XCD locality heuristic only)
    const int mem = (bid >> 3) & 15;
    const int M0  = grp * 128;
    const int HC0 = mem * 16;
    const int hc  = HC0 + (lane & 15);
    unsigned* bar = ctl + grp * 64;

    for (int dir = 0; dir < 2; ++dir) {
        __syncthreads();
        // zero both LDS h tiles (initial state per direction)
#pragma unroll
        for (int i = 0; i < 32; ++i)
            *(f32x4*)(lds + (((size_t)tid + (i << 8)) << 4)) = (f32x4){0.f, 0.f, 0.f, 0.f};
        __syncthreads();

        const int nst = dir ? RSTEPS : FSTEPS;
        const bf16x8* P0v = (const bf16x8*)(dir ? P0r_ : P0f_) + (size_t)mem * (8 * 4 * 64);
        const bf16x8* P1v = (const bf16x8*)(dir ? P1r_ : P1f_) + (size_t)mem * (16 * 4 * 64);
        const float* bs1 = dir ? bs1r : bs1f;
        float b1reg[4];
#pragma unroll
        for (int g = 0; g < 4; ++g) b1reg[g] = bs1[g * 256 + hc];

        float c0[2][4], c1[2][4];
#pragma unroll
        for (int m = 0; m < 2; ++m)
#pragma unroll
            for (int r = 0; r < 4; ++r) { c0[m][r] = 0.f; c1[m][r] = 0.f; }

        for (int t = 0; t < nst; ++t) {
            const int p0 = t & 1;          // write parity (h0 this step, h1 this step)
            const int p1 = (t + 1) & 1;    // h1 read parity = (t-1)&1

            // ---- xq: per-lane gate preactivations from xproj (normal loads, L2/L3) ----
            const int vf = dir ? (32 + t) : t;
            const _Float16* xpb = xp + ((size_t)vf * 2048 + M0) * 1024;
            float xq[4][2][4];
#pragma unroll
            for (int g = 0; g < 4; ++g)
#pragma unroll
                for (int m = 0; m < 2; ++m)
#pragma unroll
                    for (int r = 0; r < 4; ++r) {
                        int rowin = wv * 32 + m * 16 + ((lane >> 4) << 2) + r;
                        xq[g][m][r] = (float)xpb[(size_t)rowin * 1024 + g * 256 + hc];
                    }

            // ======== layer0: acc = H0s(h0prev) @ Whh0^T ========
            f32x4 acc[4][2];
#pragma unroll
            for (int g = 0; g < 4; ++g) { acc[g][0] = (f32x4){0.f,0.f,0.f,0.f}; acc[g][1] = (f32x4){0.f,0.f,0.f,0.f}; }
#pragma unroll
            for (int kc = 0; kc < 8; ++kc) {
                const int kk = kc * 32 + ((lane >> 4) << 3);
                bf16x8 a0 = ldsA(H0s, wv * 32 + (lane & 15), kk);
                bf16x8 a1 = ldsA(H0s, wv * 32 + 16 + (lane & 15), kk);
#pragma unroll
                for (int g = 0; g < 4; ++g) {
                    bf16x8 b = P0v[(kc * 4 + g) * 64 + lane];
                    acc[g][0] = MFMA_BF16(a0, b, acc[g][0]);
                    acc[g][1] = MFMA_BF16(a1, b, acc[g][1]);
                }
            }
            // epilogue0: LSTM cell (c in regs), h0 -> packed sc1 stores
            float hn0[2][4];
#pragma unroll
            for (int m = 0; m < 2; ++m)
#pragma unroll
                for (int r = 0; r < 4; ++r) {
                    float gi = acc[0][m][r] + xq[0][m][r];
                    float gf = acc[1][m][r] + xq[1][m][r];
                    float gg = acc[2][m][r] + xq[2][m][r];
                    float go = acc[3][m][r] + xq[3][m][r];
                    float cn = sigm(gf) * c0[m][r] + sigm(gi) * tanh_fast(gg);
                    c0[m][r] = cn;
                    hn0[m][r] = sigm(go) * tanh_fast(cn);
                }
            store_h_packed(h0g + (size_t)p0 * HPAR32, hn0, M0, wv, lane, HC0);

            // ---- the one barrier per step ----
            gbar16(bar);

            // ---- reload LDS tiles: h0cur(t) and h1cur(t-1) ----
            reload_h(H0s, (const u64*)(h0g + (size_t)p0 * HPAR32), M0, tid);
            if (t > 0)
                reload_h(H1s, (const u64*)(h1g + (size_t)p1 * HPAR32), M0, tid);
            __syncthreads();

            // ======== layer1: acc = [H0s(h0cur) | H1s(h1prev)] @ W1^T ========
#pragma unroll
            for (int g = 0; g < 4; ++g) { acc[g][0] = (f32x4){0.f,0.f,0.f,0.f}; acc[g][1] = (f32x4){0.f,0.f,0.f,0.f}; }
#pragma unroll
            for (int kc = 0; kc < 16; ++kc) {
                const int kk = (kc & 7) * 32 + ((lane >> 4) << 3);
                const char* Hs = (kc < 8) ? H0s : H1s;
                bf16x8 a0 = ldsA(Hs, wv * 32 + (lane & 15), kk);
                bf16x8 a1 = ldsA(Hs, wv * 32 + 16 + (lane & 15), kk);
#pragma unroll
                for (int g = 0; g < 4; ++g) {
                    bf16x8 b = P1v[(kc * 4 + g) * 64 + lane];
                    acc[g][0] = MFMA_BF16(a0, b, acc[g][0]);
                    acc[g][1] = MFMA_BF16(a1, b, acc[g][1]);
                }
            }
            float hn1[2][4];
#pragma unroll
            for (int m = 0; m < 2; ++m)
#pragma unroll
                for (int r = 0; r < 4; ++r) {
                    float gi = acc[0][m][r] + b1reg[0];
                    float gf = acc[1][m][r] + b1reg[1];
                    float gg = acc[2][m][r] + b1reg[2];
                    float go = acc[3][m][r] + b1reg[3];
                    float cn = sigm(gf) * c1[m][r] + sigm(gi) * tanh_fast(gg);
                    c1[m][r] = cn;
                    hn1[m][r] = sigm(go) * tanh_fast(cn);
                }
            store_h_packed(h1g + (size_t)p0 * HPAR32, hn1, M0, wv, lane, HC0);
            if (t == nst - 1) {
#pragma unroll
                for (int m = 0; m < 2; ++m)
#pragma unroll
                    for (int r = 0; r < 4; ++r) {
                        int row = M0 + wv * 32 + m * 16 + ((lane >> 4) << 2) + r;
                        latent[(size_t)row * 512 + dir * 256 + hc] = hn1[m][r];
                    }
            }
        }
    }
}

// ---------------- x-projection GEMM (unchanged from r2, passes @4.9e-4) ----------------
__global__ void __launch_bounds__(256)
xproj_gemm(const float* __restrict__ xs,
           const u16* __restrict__ W0xf, const u16* __restrict__ W0xr,
           const float* __restrict__ bs0f, const float* __restrict__ bs0r,
           _Float16* __restrict__ xp)
{
    __shared__ char As[16384];
    __shared__ char Bs[16384];
    const int tid = threadIdx.x, wv = tid >> 6, lane = tid & 63;
    const int phys = blockIdx.x;
    const int xcd = phys & 7, idx = phys >> 3;
    const int mt = xcd * 70 + (idx >> 3);     // 0..559
    const int nt = idx & 7;
    const int vf = mt >> 4;
    const int dirr = (vf >= 32);
    const int frame = dirr ? (95 - vf) : (30 + vf);
    const int brow = (mt & 15) * 128;
    const u16* Wp = (dirr ? W0xr : W0xf) + (size_t)nt * 128 * 512;
    const float* bs = dirr ? bs0r : bs0f;

    float breg[8];
#pragma unroll
    for (int n = 0; n < 8; ++n) breg[n] = bs[nt * 128 + n * 16 + (lane & 15)];

    f32x4 acc[8][2];
#pragma unroll
    for (int n = 0; n < 8; ++n) { acc[n][0] = (f32x4){0.f,0.f,0.f,0.f}; acc[n][1] = (f32x4){0.f,0.f,0.f,0.f}; }

    const int ar = tid >> 1, akoff = (tid & 1) * 32;
    const float* asrc0 = xs + ((size_t)(brow + ar) * 64 + frame) * 512 + akoff;

    for (int c = 0; c < 8; ++c) {
        {   // stage A: 128 rows x 64 k, fp32 -> bf16
            const float* s = asrc0 + c * 64;
            u16x8 o[4];
#pragma unroll
            for (int j2 = 0; j2 < 4; ++j2) {
                float4 f0 = *(const float4*)(s + j2 * 8);
                float4 f1 = *(const float4*)(s + j2 * 8 + 4);
                u16x8 o_;
                o_[0] = f2bf(f0.x); o_[1] = f2bf(f0.y); o_[2] = f2bf(f0.z); o_[3] = f2bf(f0.w);
                o_[4] = f2bf(f1.x); o_[5] = f2bf(f1.y); o_[6] = f2bf(f1.z); o_[7] = f2bf(f1.w);
                o[j2] = o_;
            }
#pragma unroll
            for (int j2 = 0; j2 < 4; ++j2) {
                int k = akoff + j2 * 8;
                int byte = (ar << 7) + (k << 1); byte ^= (ar & 7) << 4;
                *(u16x8*)(As + byte) = o[j2];
            }
        }
#pragma unroll
        for (int i = 0; i < 4; ++i) {   // stage B: 128 rows x 64 k
            int u = tid + i * 256;
            int ns = u >> 3, c8 = (u & 7) << 3;
            u16x8 v = *(const u16x8*)(Wp + (size_t)ns * 512 + c * 64 + c8);
            int byte = (ns << 7) + (c8 << 1); byte ^= (ns & 7) << 4;
            *(u16x8*)(Bs + byte) = v;
        }
        __syncthreads();
#pragma unroll
        for (int kk = 0; kk < 2; ++kk) {
            int kin = kk * 32 + (lane >> 4) * 8;
            bf16x8 a0, a1;
            int row = wv * 32 + (lane & 15);
            int byte = (row << 7) + (kin << 1); byte ^= (row & 7) << 4;
            a0 = *(const bf16x8*)(As + byte);
            int row1 = row + 16;
            byte = (row1 << 7) + (kin << 1); byte ^= (row1 & 7) << 4;
            a1 = *(const bf16x8*)(As + byte);
#pragma unroll
            for (int n = 0; n < 8; ++n) {
                int ns = n * 16 + (lane & 15);
                int bb = (ns << 7) + (kin << 1); bb ^= (ns & 7) << 4;
                bf16x8 bf_ = *(const bf16x8*)(Bs + bb);
                acc[n][0] = MFMA_BF16(a0, bf_, acc[n][0]);
                acc[n][1] = MFMA_BF16(a1, bf_, acc[n][1]);
            }
        }
        __syncthreads();
    }
#pragma unroll
    for (int n = 0; n < 8; ++n)
#pragma unroll
        for (int m = 0; m < 2; ++m)
#pragma unroll
            for (int r = 0; r < 4; ++r) {
                int vm = mt * 128 + wv * 32 + m * 16 + ((lane >> 4) << 2) + r;
                int col = nt * 128 + n * 16 + (lane & 15);
                xp[(size_t)vm * 1024 + col] = (_Float16)(acc[n][m][r] + breg[n]);
            }
}

// ---------------- prep kernels ----------------
// row-major pack for xproj B + bias sum
__global__ void pack_w(const float* __restrict__ Wa, int da,
                       const float* __restrict__ bi, const float* __restrict__ bh,
                       u16* __restrict__ Wout, float* __restrict__ bout)
{
    int total = 1024 * da;
    int gt = blockIdx.x * blockDim.x + threadIdx.x;
    int stride = gridDim.x * blockDim.x;
    for (int i = gt; i < total; i += stride) Wout[i] = f2bf(Wa[i]);
    if (bout && gt < 1024) bout[gt] = bi[gt] + bh[gt];
}

// fragment-ordered pack: unit u (16B) -> l=u&63, g=(u>>6)&3, kc, mem;
// row = g*256 + mem*16 + (l&15); k0 = kc*32 + (l>>4)*8;  K = 32*nkc = da+db
__global__ void pack_frag(const float* __restrict__ Wa, int da,
                          const float* __restrict__ Wb, int db,
                          int nkc, u16* __restrict__ out,
                          const float* __restrict__ bi, const float* __restrict__ bh,
                          float* __restrict__ bout)
{
    int total = 16 * nkc * 4 * 64;
    int gt = blockIdx.x * blockDim.x + threadIdx.x;
    int stride = gridDim.x * blockDim.x;
    for (int u = gt; u < total; u += stride) {
        int l = u & 63;
        int t1 = u >> 6;
        int g = t1 & 3;
        int t2 = t1 >> 2;
        int kc = t2 % nkc;
        int mem = t2 / nkc;
        int row = g * 256 + mem * 16 + (l & 15);
        int k0 = kc * 32 + ((l >> 4) << 3);
        u16x8 o;
#pragma unroll
        for (int j = 0; j < 8; ++j) {
            int k = k0 + j;
            float v = (k < da) ? Wa[(size_t)row * da + k] : Wb[(size_t)row * db + (k - da)];
            o[j] = f2bf(v);
        }
        *(u16x8*)(out + (size_t)u * 8) = o;
    }
    if (bout && gt < 1024) bout[gt] = bi[gt] + bh[gt];
}

// ---------------- final linear ----------------
__global__ void final_linear(const float* __restrict__ latent, const float* __restrict__ W3,
                             const float* __restrict__ b3, float* __restrict__ out)
{
    int idx = blockIdx.x * blockDim.x + threadIdx.x;
    if (idx >= BATCH * 10) return;
    int bb = idx / 10, c = idx - bb * 10;
    const float* lrow = latent + (size_t)bb * 512;
    const float* wrow = W3 + (size_t)c * 512;
    float s = b3[c];
#pragma unroll 4
    for (int k = 0; k < 512; k += 4) {
        float4 lv = *(const float4*)(lrow + k);
        float4 wv = *(const float4*)(wrow + k);
        s += lv.x * wv.x + lv.y * wv.y + lv.z * wv.z + lv.w * wv.w;
    }
    out[idx] = s;
}

// ---------------- launch ----------------
extern "C" void kernel_launch(void* const* d_in, const int* in_sizes, int n_in,
                              void* d_out, int out_size, void* d_ws, size_t ws_size,
                              hipStream_t stream)
{
    (void)in_sizes; (void)n_in; (void)out_size;
    if (ws_size < WS_NEED) return;   // leaves d_out poisoned -> diagnosable as ws shortfall

    const float* xs     = (const float*)d_in[0];
    const float* Wih_f0 = (const float*)d_in[1];
    const float* Whh_f0 = (const float*)d_in[2];
    const float* bih_f0 = (const float*)d_in[3];
    const float* bhh_f0 = (const float*)d_in[4];
    const float* Wih_f1 = (const float*)d_in[5];
    const float* Whh_f1 = (const float*)d_in[6];
    const float* bih_f1 = (const float*)d_in[7];
    const float* bhh_f1 = (const float*)d_in[8];
    const float* Wih_r0 = (const float*)d_in[9];
    const float* Whh_r0 = (const float*)d_in[10];
    const float* bih_r0 = (const float*)d_in[11];
    const float* bhh_r0 = (const float*)d_in[12];
    const float* Wih_r1 = (const float*)d_in[13];
    const float* Whh_r1 = (const float*)d_in[14];
    const float* bih_r1 = (const float*)d_in[15];
    const float* bhh_r1 = (const float*)d_in[16];
    const float* W3     = (const float*)d_in[17];
    const float* b3     = (const float*)d_in[18];

    char* ws = (char*)d_ws;
    unsigned* ctl = (unsigned*)(ws + OFF_CTL);
    unsigned* h0g = (unsigned*)(ws + OFF_H0G);
    unsigned* h1g = (unsigned*)(ws + OFF_H1G);
    float* latent = (float*)(ws + OFF_LAT);
    _Float16* xp  = (_Float16*)(ws + OFF_XP);
    u16* W0xf = (u16*)(ws + OFF_W0XF);
    u16* W0xr = (u16*)(ws + OFF_W0XR);
    u16* P0f  = (u16*)(ws + OFF_P0F);
    u16* P0r  = (u16*)(ws + OFF_P0R);
    u16* P1f  = (u16*)(ws + OFF_P1F);
    u16* P1r  = (u16*)(ws + OFF_P1R);
    float* bs0f = (float*)(ws + OFF_BS0F);
    float* bs0r = (float*)(ws + OFF_BS0R);
    float* bs1f = (float*)(ws + OFF_BS1F);
    float* bs1r = (float*)(ws + OFF_BS1R);

    hipMemsetAsync(ctl, 0, 4096, stream);   // barrier flags only

    pack_w<<<256, 256, 0, stream>>>(Wih_f0, 512, bih_f0, bhh_f0, W0xf, bs0f);
    pack_w<<<256, 256, 0, stream>>>(Wih_r0, 512, bih_r0, bhh_r0, W0xr, bs0r);
    pack_frag<<<64, 256, 0, stream>>>(Whh_f0, 256, Whh_f0, 0, 8,  P0f, nullptr, nullptr, nullptr);
    pack_frag<<<64, 256, 0, stream>>>(Whh_r0, 256, Whh_r0, 0, 8,  P0r, nullptr, nullptr, nullptr);
    pack_frag<<<64, 256, 0, stream>>>(Wih_f1, 256, Whh_f1, 256, 16, P1f, bih_f1, bhh_f1, bs1f);
    pack_frag<<<64, 256, 0, stream>>>(Wih_r1, 256, Whh_r1, 256, 16, P1r, bih_r1, bhh_r1, bs1r);

    xproj_gemm<<<4480, 256, 0, stream>>>(xs, W0xf, W0xr, bs0f, bs0r, xp);

    hipFuncSetAttribute((const void*)lstm_seq,
                        hipFuncAttributeMaxDynamicSharedMemorySize, 131072);
    lstm_seq<<<256, 256, 131072, stream>>>(xp, P0f, P0r, P1f, P1r, bs1f, bs1r,
                                           h0g, h1g, latent, ctl);

    final_linear<<<80, 256, 0, stream>>>(latent, W3, b3, (float*)d_out);
}